// Round 5
// baseline (2006.881 us; speedup 1.0000x reference)
//
#include <hip/hip_runtime.h>
#include <hip/hip_bf16.h>

// ELMo 2-layer biLSTM, B=64 T=256 U=256. Persistent RNN, chain-pipelined:
//  - 32 WGs = 2 dirs x 16 unit-slices; 512 thr (8 waves = gate g x K-half kh).
//  - Weights in VGPRs (16 frags/wave). LDS: mask 16K + zpart 16K + 2x8K h tiles.
//  - Each WG runs ALL 4 rowgroup chains of its dir; per tick 4 slots.
//    Slot c: spin flags[c+1] -> issue chain c+1 h/emb loads (asm, untracked) ->
//    vmcnt(6) [counted: drains chain c loads + prev stores, keeps new 6] ->
//    emb MFMA -> stage h to LDS -> raw barrier -> publish flag[c-1] ->
//    h MFMAs -> zpart -> barrier -> combine -> H-store (sc1) + out store.
//  - All barriers raw s_barrier + manual lgkmcnt(0) (no compiler vmcnt drain).

#define TT 256
#define TM 255
#define NU 256
#define NG 1024
#define BB 64
#define NTICK 256

typedef __attribute__((ext_vector_type(8))) short short8;
typedef __attribute__((ext_vector_type(4))) float f32x4;
typedef __attribute__((ext_vector_type(4))) unsigned int u32x4;

__device__ __forceinline__ unsigned short f2bf(float v) {
  unsigned int x = __float_as_uint(v);
  return (unsigned short)((x + 0x7FFFu + ((x >> 16) & 1u)) >> 16);
}
__device__ __forceinline__ float sigm(float x) { return 1.f / (1.f + __expf(-x)); }
__device__ __forceinline__ float tanhp(float x) {
  x = fminf(fmaxf(x, -15.f), 15.f);
  float e = __expf(-2.f * x);
  return (1.f - e) / (1.f + e);
}
__device__ __forceinline__ u32x4 llc_load16(const void* p) {  // LLC-coherent
  u32x4 r;
  asm volatile("global_load_dwordx4 %0, %1, off sc0 sc1" : "=v"(r) : "v"(p));
  return r;
}
__device__ __forceinline__ u32x4 cach_load16(const void* p) {  // cached, untracked
  u32x4 r;
  asm volatile("global_load_dwordx4 %0, %1, off" : "=v"(r) : "v"(p));
  return r;
}
#define VMCNT(n) asm volatile("s_waitcnt vmcnt(" #n ")" ::: "memory")
#define LGKM0() asm volatile("s_waitcnt lgkmcnt(0)" ::: "memory")
#define SCHEDBAR() __builtin_amdgcn_sched_barrier(0)
#define BAR() __builtin_amdgcn_s_barrier()

__global__ void embed_kernel(const int* __restrict__ seqs, const float* __restrict__ E,
                             unsigned short* __restrict__ embb, float* __restrict__ out) {
  int b = blockIdx.x, t = blockIdx.y, d = threadIdx.x;
  int s = seqs[b * TT + t];
  float v = E[(size_t)s * NU + d];
  embb[((size_t)(b * TT + t)) * NU + d] = f2bf(v);
  if (t < TM) out[(((size_t)(0 * BB + b)) * TM + t) * NU + d] = v;
  if (t >= 1) out[(((size_t)(3 * BB + b)) * TM + (t - 1)) * NU + d] = v;
}

__launch_bounds__(512, 1)
__global__ void lstm_kernel(const int* __restrict__ seqs,
                            const float* __restrict__ Wf, const float* __restrict__ Uf,
                            const float* __restrict__ bf,
                            const float* __restrict__ Wb, const float* __restrict__ Ub,
                            const float* __restrict__ bb,
                            const unsigned short* __restrict__ embb,
                            unsigned short* __restrict__ H0, unsigned short* __restrict__ H1,
                            int* __restrict__ ctr, float* __restrict__ out) {
  extern __shared__ char smem[];
  unsigned char* mskl = (unsigned char*)smem;  // [64 rows][256 steps] = 16KB
  float* zpart = (float*)(smem + 16384);       // [2][4][2][16][16] f32 = 16KB
  char* hlb0 = smem + 32768;                   // 8KB swizzled h0 tile
  char* hlb1 = smem + 40960;                   // 8KB swizzled h1 tile

  const int tid = threadIdx.x;
  const int dirb = blockIdx.x >> 4;
  const int slice = blockIdx.x & 15;
  const int ubase = slice << 4;
  const int wave = tid >> 6, g = wave & 3, kh = wave >> 2;
  const int lane = tid & 63, q = lane >> 4, n15 = lane & 15;
  const int tlay = tid >> 8, ct = tid & 255, crow = ct >> 4, cn = ct & 15;

  const float* W0 = dirb ? Wb : Wf;
  const float* U0 = dirb ? Ub : Uf;
  const float* b0p = dirb ? bb : bf;
  const float* mats[4] = {W0, U0, W0 + NU * NG, U0 + NU * NG};

  // ---- weights -> VGPRs: wreg[m*4+kb], element k = kh*128+kb*32+q*8+j, col = g*256+ubase+n15
  short8 wreg[16];
  {
    const int col = g * 256 + ubase + n15;
    #pragma unroll
    for (int m = 0; m < 4; m++) {
      #pragma unroll
      for (int kb = 0; kb < 4; kb++) {
        short8 t;
        #pragma unroll
        for (int j = 0; j < 8; j++)
          t[j] = (short)f2bf(mats[m][(size_t)(kh * 128 + kb * 32 + q * 8 + j) * NG + col]);
        wreg[m * 4 + kb] = t;
      }
    }
  }

  // ---- mask table (LDS)
  for (int i = tid; i < 64 * 256; i += 512) {
    int row = i >> 8, s = i & 255;
    unsigned char mv = 0;
    if (s < TM) mv = (seqs[row * TT + (dirb ? TM - s : s)] != 0);
    mskl[i] = mv;
  }

  // ---- per-combine-thread bias + per-chain state
  float bi[4];
  {
    const float* bp = tlay ? (b0p + NG) : b0p;
    #pragma unroll
    for (int gg = 0; gg < 4; gg++) bi[gg] = bp[(gg << 8) + ubase + cn];
  }
  float cst[4] = {0.f, 0.f, 0.f, 0.f}, hv[4] = {0.f, 0.f, 0.f, 0.f};

  int* flg = ctr + dirb * 64;  // [chain][slice]
  const int wsw = (tid * 16) ^ (((tid >> 5) & 7) << 4);
  const int fb = n15 * 512 + kh * 256, fx = (n15 & 7) << 4;

  LGKM0();
  SCHEDBAR();
  BAR();  // mask visible

  u32x4 embR[2][4];
  u32x4 ldh0R[2], ldh1R[2];

  // ================= prologue: tick 0 (emb-only, no cross-WG deps) =================
  #pragma unroll
  for (int c = 0; c < 4; c++) {
    const unsigned short* ep =
        embb + ((size_t)((c * 16 + n15) * TT + (dirb ? TM : 0))) * NU + kh * 128 + q * 8;
    #pragma unroll
    for (int kb = 0; kb < 4; kb++) embR[0][kb] = cach_load16(ep + kb * 32);
    VMCNT(0);
    SCHEDBAR();
    f32x4 acc0 = {0.f, 0.f, 0.f, 0.f};
    #pragma unroll
    for (int kb = 0; kb < 4; kb++)
      acc0 = __builtin_amdgcn_mfma_f32_16x16x32_bf16(*(short8*)&embR[0][kb], wreg[kb], acc0, 0, 0, 0);
    #pragma unroll
    for (int j = 0; j < 4; j++) zpart[(g * 2 + kh) * 256 + ((q * 4 + j) << 4) + n15] = acc0[j];
    LGKM0();
    SCHEDBAR();
    BAR();
    if (tlay == 0) {
      float z[4];
      #pragma unroll
      for (int gg = 0; gg < 4; gg++)
        z[gg] = zpart[(gg * 2 + 0) * 256 + crow * 16 + cn] +
                zpart[(gg * 2 + 1) * 256 + crow * 16 + cn] + bi[gg];
      float cnw = sigm(z[0]) * tanhp(z[2]);
      float hnw = sigm(z[3]) * tanhp(cnw);
      if (mskl[(c * 16 + crow) * 256 + 0]) { cst[c] = cnw; hv[c] = hnw; }
      unsigned hb = f2bf(hv[c]);
      unsigned ot = (unsigned)__shfl_xor((int)hb, 1, 64);
      if (!(cn & 1)) {
        unsigned pk = (hb & 0xFFFFu) | (ot << 16);
        __hip_atomic_store((unsigned*)(H0 + (((0 * 2 + dirb) * 4 + c) * 16 + crow) * 256 + ubase + cn),
                           pk, __ATOMIC_RELAXED, __HIP_MEMORY_SCOPE_AGENT);
      }
      int tout = dirb ? TM - 1 : 0;
      out[(((size_t)((1 + dirb * 3) * BB + c * 16 + crow)) * TM + tout) * NU + ubase + cn] = hv[c];
    }
    VMCNT(0);
    SCHEDBAR();
    BAR();  // all waves' stores ack'd before flag
    if (tid == 0)
      __hip_atomic_store(flg + c * 16 + slice, 1, __ATOMIC_RELAXED, __HIP_MEMORY_SCOPE_AGENT);
    BAR();  // zpart reuse guard
  }

  // ---- pre-steady: spin chain0 tick0, issue chain0@tau=1 loads into bank 0
  if (wave == 0) {
    for (;;) {
      int v = 0x7fffffff;
      if (lane < 16) v = __hip_atomic_load(flg + lane, __ATOMIC_RELAXED, __HIP_MEMORY_SCOPE_AGENT);
      if (__all(v >= 1)) break;
    }
  }
  BAR();
  {
    const unsigned short* s0 = H0 + ((0 * 2 + dirb) * 4 + 0) * 4096;  // parity 0, chain 0
    const unsigned short* s1 = H1 + ((0 * 2 + dirb) * 4 + 0) * 4096;
    ldh0R[0] = llc_load16(s0 + tid * 8);
    ldh1R[0] = llc_load16(s1 + tid * 8);
    const unsigned short* ep =
        embb + ((size_t)((0 * 16 + n15) * TT + (dirb ? TM - 1 : 1))) * NU + kh * 128 + q * 8;
    #pragma unroll
    for (int kb = 0; kb < 4; kb++) embR[0][kb] = cach_load16(ep + kb * 32);
  }

  // ================= steady loop: tau = 1..255, 4 chain-slots per tick =================
  for (int tau = 1; tau < NTICK; ++tau) {
    const bool doL0 = (tau < TM);
    #pragma unroll
    for (int c = 0; c < 4; c++) {
      const int cb = c & 1, nb = cb ^ 1;
      const bool lastslot = (tau == TM) && (c == 3);
      const int cn1 = (c + 1) & 3;
      const int tnext = (c == 3) ? tau + 1 : tau;  // consumer tick of chain cn1

      // 1. spin for chain cn1's tick (tnext-1) publication
      if (!lastslot && wave == 0) {
        const int* fl = flg + cn1 * 16;
        for (;;) {
          int v = 0x7fffffff;
          if (lane < 16) v = __hip_atomic_load(fl + lane, __ATOMIC_RELAXED, __HIP_MEMORY_SCOPE_AGENT);
          if (__all(v >= tnext)) break;
        }
      }
      BAR();  // release spin; LDS h/zpart reuse guard

      // 2. issue chain cn1 loads (6 per thread) into bank nb
      if (!lastslot) {
        const int pbn = (tnext + 1) & 1;
        const unsigned short* s0 = H0 + ((pbn * 2 + dirb) * 4 + cn1) * 4096;
        const unsigned short* s1 = H1 + ((pbn * 2 + dirb) * 4 + cn1) * 4096;
        ldh0R[nb] = llc_load16(s0 + tid * 8);
        ldh1R[nb] = llc_load16(s1 + tid * 8);
        const unsigned short* ep =
            embb + ((size_t)((cn1 * 16 + n15) * TT + (dirb ? TM - tnext : tnext))) * NU +
            kh * 128 + q * 8;
        #pragma unroll
        for (int kb = 0; kb < 4; kb++) embR[nb][kb] = cach_load16(ep + kb * 32);
        VMCNT(6);  // drain chain c's 6 loads + prev slot's stores; keep new 6
        SCHEDBAR();
      } else {
        VMCNT(0);
        SCHEDBAR();
      }

      // 3. emb MFMAs (no LDS dep) overlap staging
      f32x4 acc0 = {0.f, 0.f, 0.f, 0.f}, acc1 = {0.f, 0.f, 0.f, 0.f};
      if (doL0) {
        #pragma unroll
        for (int kb = 0; kb < 4; kb++)
          acc0 = __builtin_amdgcn_mfma_f32_16x16x32_bf16(*(short8*)&embR[cb][kb], wreg[kb], acc0, 0, 0, 0);
      }

      // 4. stage chain c's h tiles (loaded last slot) to swizzled LDS
      *(u32x4*)(hlb0 + wsw) = ldh0R[cb];
      *(u32x4*)(hlb1 + wsw) = ldh1R[cb];
      LGKM0();
      SCHEDBAR();
      BAR();  // every wave past its VMCNT -> all prev-slot stores ack'd

      // 5. publish flag for chain computed last slot
      if (tid == 0) {
        int pc = (c + 3) & 3;
        int pv = (c == 0) ? tau : tau + 1;
        __hip_atomic_store(flg + pc * 16 + slice, pv, __ATOMIC_RELAXED, __HIP_MEMORY_SCOPE_AGENT);
      }

      // 6. h MFMAs: h0 @ U0 (L0) + h0 @ W1 (L1) + h1 @ U1 (L1, tau>=2)
      #pragma unroll
      for (int kb = 0; kb < 4; kb++) {
        short8 h0f = *(const short8*)(hlb0 + ((fb + kb * 64 + q * 16) ^ fx));
        if (doL0) acc0 = __builtin_amdgcn_mfma_f32_16x16x32_bf16(h0f, wreg[4 + kb], acc0, 0, 0, 0);
        acc1 = __builtin_amdgcn_mfma_f32_16x16x32_bf16(h0f, wreg[8 + kb], acc1, 0, 0, 0);
      }
      if (tau >= 2) {
        #pragma unroll
        for (int kb = 0; kb < 4; kb++) {
          short8 h1f = *(const short8*)(hlb1 + ((fb + kb * 64 + q * 16) ^ fx));
          acc1 = __builtin_amdgcn_mfma_f32_16x16x32_bf16(h1f, wreg[12 + kb], acc1, 0, 0, 0);
        }
      }

      // 7. z partials
      if (doL0) {
        #pragma unroll
        for (int j = 0; j < 4; j++)
          zpart[(g * 2 + kh) * 256 + ((q * 4 + j) << 4) + n15] = acc0[j];
      }
      #pragma unroll
      for (int j = 0; j < 4; j++)
        zpart[((4 + g) * 2 + kh) * 256 + ((q * 4 + j) << 4) + n15] = acc1[j];
      LGKM0();
      SCHEDBAR();
      BAR();

      // 8. combine: waves 0-3 = L0 (step tau), waves 4-7 = L1 (step tau-1)
      {
        const int step = tlay ? tau - 1 : tau;
        const bool act = tlay ? true : doL0;
        if (act) {
          float z[4];
          #pragma unroll
          for (int gg = 0; gg < 4; gg++)
            z[gg] = zpart[((tlay * 4 + gg) * 2 + 0) * 256 + crow * 16 + cn] +
                    zpart[((tlay * 4 + gg) * 2 + 1) * 256 + crow * 16 + cn] + bi[gg];
          float cnw = sigm(z[1]) * cst[c] + sigm(z[0]) * tanhp(z[2]);
          float hnw = sigm(z[3]) * tanhp(cnw);
          if (mskl[(c * 16 + crow) * 256 + step]) { cst[c] = cnw; hv[c] = hnw; }
          unsigned hb = f2bf(hv[c]);
          unsigned ot = (unsigned)__shfl_xor((int)hb, 1, 64);
          unsigned short* Hp = tlay ? H1 : H0;
          if (!(cn & 1)) {
            unsigned pk = (hb & 0xFFFFu) | (ot << 16);
            __hip_atomic_store(
                (unsigned*)(Hp + (((tau & 1) * 2 + dirb) * 4 + c) * 4096 + crow * 256 + ubase + cn),
                pk, __ATOMIC_RELAXED, __HIP_MEMORY_SCOPE_AGENT);
          }
          int tout = dirb ? TM - 1 - step : step;
          out[(((size_t)((1 + tlay + dirb * 3) * BB + c * 16 + crow)) * TM + tout) * NU + ubase + cn] =
              hv[c];
        }
      }
    }
  }
}

extern "C" void kernel_launch(void* const* d_in, const int* in_sizes, int n_in,
                              void* d_out, int out_size, void* d_ws, size_t ws_size,
                              hipStream_t stream) {
  const int* seqs = (const int*)d_in[0];
  const float* E = (const float*)d_in[1];
  const float* Wf = (const float*)d_in[2];
  const float* Uf = (const float*)d_in[3];
  const float* bfp = (const float*)d_in[4];
  const float* Wb = (const float*)d_in[5];
  const float* Ub = (const float*)d_in[6];
  const float* bbp = (const float*)d_in[7];
  float* out = (float*)d_out;

  char* ws = (char*)d_ws;
  int* ctr = (int*)ws;                                           // 512B flags
  unsigned short* embb = (unsigned short*)(ws + 65536);          // 8MB bf16 emb
  unsigned short* H0 = (unsigned short*)(ws + 65536 + 8388608);  // 128KB
  unsigned short* H1 = H0 + 65536;                               // 128KB

  hipMemsetAsync(ctr, 0, 512, stream);

  hipLaunchKernelGGL(embed_kernel, dim3(BB, TT), dim3(256), 0, stream,
                     seqs, E, embb, out);

  int smem = 49152;  // 16K mask + 16K zpart + 2x8K h tiles
  hipFuncSetAttribute(reinterpret_cast<const void*>(lstm_kernel),
                      hipFuncAttributeMaxDynamicSharedMemorySize, smem);
  hipLaunchKernelGGL(lstm_kernel, dim3(32), dim3(512), smem, stream,
                     seqs, Wf, Uf, bfp, Wb, Ub, bbp, embb, H0, H1, ctr, out);
}

// Round 6
// 798.428 us; speedup vs baseline: 2.5135x; 2.5135x over previous
//
#include <hip/hip_runtime.h>
#include <hip/hip_bf16.h>

// ELMo 2-layer biLSTM, B=64 T=256 U=256. Persistent RNN, DATA-TAGGED sync:
//  - 128 WGs = 8 clusters (4 rowgroups x 2 dirs, cluster=blk&7 -> same XCD) x 16 slices.
//  - 512 thr (8 waves = gate g x K-half kh); weight slices bf16 in LDS (128KB).
//  - h exchange: each h unit stored as u32 (tag=tick+1)<<16 | bf16, relaxed sc1,
//    fire-and-forget (NO flags, NO drains). Consumers poll their 32B until all
//    tags==tau, strip tags -> swizzled LDS tile -> ds_read_b128 frags.
//  - 2-deep parity ring is race-free: producing tag t+2 requires all slices
//    consumed tag t+1 (dependency chain bounds skew to 1 tick).

#define TT 256
#define TM 255
#define NU 256
#define NG 1024
#define BB 64

typedef __attribute__((ext_vector_type(8))) short short8;
typedef __attribute__((ext_vector_type(4))) float f32x4;
typedef __attribute__((ext_vector_type(4))) unsigned int u32x4;

__device__ __forceinline__ unsigned short f2bf(float v) {
  unsigned int x = __float_as_uint(v);
  return (unsigned short)((x + 0x7FFFu + ((x >> 16) & 1u)) >> 16);
}
__device__ __forceinline__ float sigm(float x) { return 1.f / (1.f + __expf(-x)); }
__device__ __forceinline__ float tanhp(float x) {
  x = fminf(fmaxf(x, -15.f), 15.f);
  float e = __expf(-2.f * x);
  return (1.f - e) / (1.f + e);
}
__device__ __forceinline__ u32x4 llc_load16(const unsigned int* p) {
  u32x4 r;
  asm volatile("global_load_dwordx4 %0, %1, off sc0 sc1" : "=v"(r) : "v"(p));
  return r;
}
#define VMCNT0() asm volatile("s_waitcnt vmcnt(0)" ::: "memory")
#define LGKM0() asm volatile("s_waitcnt lgkmcnt(0)" ::: "memory")
#define SCHEDBAR() __builtin_amdgcn_sched_barrier(0)
#define BAR() __builtin_amdgcn_s_barrier()

__global__ void embed_kernel(const int* __restrict__ seqs, const float* __restrict__ E,
                             unsigned short* __restrict__ embb, float* __restrict__ out) {
  int b = blockIdx.x, t = blockIdx.y, d = threadIdx.x;
  int s = seqs[b * TT + t];
  float v = E[(size_t)s * NU + d];
  embb[((size_t)(b * TT + t)) * NU + d] = f2bf(v);
  if (t < TM) out[(((size_t)(0 * BB + b)) * TM + t) * NU + d] = v;
  if (t >= 1) out[(((size_t)(3 * BB + b)) * TM + (t - 1)) * NU + d] = v;
}

__launch_bounds__(512, 1)
__global__ void lstm_kernel(const int* __restrict__ seqs,
                            const float* __restrict__ Wf, const float* __restrict__ Uf,
                            const float* __restrict__ bf,
                            const float* __restrict__ Wb, const float* __restrict__ Ub,
                            const float* __restrict__ bb,
                            const unsigned short* __restrict__ embb,
                            unsigned int* __restrict__ Hbuf, float* __restrict__ out) {
  extern __shared__ char smem[];
  unsigned short* wlds = (unsigned short*)smem;   // 128KB weights
  float* zpart = (float*)(smem + 131072);         // [2][4][2][16][16] f32 = 16KB
  char* hlb0 = smem + 147456;                     // 8KB swizzled h0 tile (bf16)
  char* hlb1 = smem + 155648;                     // 8KB swizzled h1 tile

  const int tid = threadIdx.x;
  const int blk = blockIdx.x;
  const int cluster = blk & 7, slice = blk >> 3;  // cluster -> same XCD (L2 locality)
  const int dir = cluster >> 2, rg = cluster & 3;
  const int ubase = slice << 4;
  const int wave = tid >> 6, g = wave & 3, kh = wave >> 2;
  const int lane = tid & 63, q = lane >> 4, n15 = lane & 15;
  const int tlay = tid >> 8, ct = tid & 255, crow = ct >> 4, cn = ct & 15;
  const int brow = rg * 16 + crow;

  const float* W0 = dir ? Wb : Wf;
  const float* U0 = dir ? Ub : Uf;
  const float* b0p = dir ? bb : bf;
  const float* mats[4] = {W0, U0, W0 + NU * NG, U0 + NU * NG};

  // ---- weights -> LDS (bf16 B-frag layout; k=kb*32+q*8+j within kh-half)
  {
    int c = tid & 63;
    int gg = c >> 4, n = c & 15;
    int col = (gg << 8) + ubase + n;
    int koff = tid >> 6;
    for (int m = 0; m < 4; m++) {
      const float* S = mats[m];
      unsigned short* WL = wlds + m * 16384;
      for (int k0 = 0; k0 < 256; k0 += 8) {
        int k = k0 + koff;
        int li = (gg << 12) + ((k >> 5) << 9) + (((k >> 3) & 3) << 7) + (n << 3) + (k & 7);
        WL[li] = f2bf(S[(size_t)k * NG + col]);
      }
    }
  }

  float bi[4];
  {
    const float* bp = tlay ? (b0p + NG) : b0p;
    #pragma unroll
    for (int gg = 0; gg < 4; gg++) bi[gg] = bp[(gg << 8) + ubase + cn];
  }
  float cst = 0.f, hv = 0.f;

  __syncthreads();

  const unsigned short* wb0 = wlds + (g << 12) + (kh << 11) + (q << 7) + (n15 << 3);
  const unsigned short* ub0 = wb0 + 16384;
  const unsigned short* wb1 = wb0 + 32768;
  const unsigned short* ub1 = wb0 + 49152;
  const int wsw = (tid * 16) ^ (((tid >> 5) & 7) << 4);
  const int fb = n15 * 512 + kh * 256;
  const int fx = (n15 & 7) << 4;
  const int zwr = (g << 9) + (kh << 8) + n15;

  // producer word slot: [(layer*2+parity)*8+cluster][4096]; parity stride 32768 words
  unsigned int* hst = Hbuf + ((size_t)(tlay * 2 * 8 + cluster)) * 4096 + crow * 256 + ubase + cn;

  // ================= tick 0: emb-only, L0 combine, store tag 1 parity 0 ============
  {
    int tx = dir ? TM : 0;
    const unsigned short* ep =
        embb + ((size_t)((rg * 16 + n15) * TT + tx)) * NU + kh * 128 + q * 8;
    f32x4 acc0 = {0.f, 0.f, 0.f, 0.f};
    #pragma unroll
    for (int kb = 0; kb < 4; kb++) {
      short8 a = *(const short8*)(ep + kb * 32);
      short8 b = *(const short8*)(wb0 + (kb << 9));
      acc0 = __builtin_amdgcn_mfma_f32_16x16x32_bf16(a, b, acc0, 0, 0, 0);
    }
    #pragma unroll
    for (int j = 0; j < 4; j++) zpart[zwr + (((q << 2) + j) << 4)] = acc0[j];
    LGKM0(); SCHEDBAR(); BAR();
    if (tlay == 0) {
      float z[4];
      #pragma unroll
      for (int gg = 0; gg < 4; gg++)
        z[gg] = zpart[(gg * 2) * 256 + crow * 16 + cn] +
                zpart[(gg * 2 + 1) * 256 + crow * 16 + cn] + bi[gg];
      float cnw = sigm(z[1]) * cst + sigm(z[0]) * tanhp(z[2]);
      float hnw = sigm(z[3]) * tanhp(cnw);
      int traw = dir ? TM : 0;
      if (seqs[brow * TT + traw] != 0) { cst = cnw; hv = hnw; }
      __hip_atomic_store(hst, (1u << 16) | (unsigned)f2bf(hv),
                         __ATOMIC_RELAXED, __HIP_MEMORY_SCOPE_AGENT);
      int tout = dir ? TM - 1 : 0;
      out[(((size_t)((1 + dir * 3) * BB + brow)) * TM + tout) * NU + ubase + cn] = hv;
    }
  }

  // ================= ticks 1..255 =================
  for (int tau = 1; tau < 256; ++tau) {
    const bool doL0 = (tau < TM);
    const bool doH1 = (tau >= 2);
    const int step = tlay ? tau - 1 : tau;

    // mask value (cached, off critical path)
    int mval = 0;
    if (tlay ? true : doL0) mval = seqs[brow * TT + (dir ? TM - step : step)];

    // emb frag loads (L2-cached; in flight during poll)
    short8 ea[4];
    if (doL0) {
      int tx = dir ? (TM - tau) : tau;
      const unsigned short* ep =
          embb + ((size_t)((rg * 16 + n15) * TT + tx)) * NU + kh * 128 + q * 8;
      #pragma unroll
      for (int kb = 0; kb < 4; kb++) ea[kb] = *(const short8*)(ep + kb * 32);
    }

    // ---- poll tagged h words (per-thread 32B of h0, +32B of h1 when doH1)
    const unsigned tg = (unsigned)tau;
    const int p = (tau + 1) & 1;  // parity of producing tick tau-1
    const unsigned int* c0 = Hbuf + ((size_t)(p * 8 + cluster)) * 4096 + tid * 8;
    const unsigned int* c1 = Hbuf + ((size_t)((2 + p) * 8 + cluster)) * 4096 + tid * 8;
    u32x4 a0 = {0,0,0,0}, a1 = {0,0,0,0}, b0v = {0,0,0,0}, b1v = {0,0,0,0};
    for (;;) {
      a0 = llc_load16(c0);
      a1 = llc_load16(c0 + 4);
      if (doH1) { b0v = llc_load16(c1); b1v = llc_load16(c1 + 4); }
      VMCNT0(); SCHEDBAR();
      bool ok = (a0[0] >> 16) == tg && (a0[1] >> 16) == tg && (a0[2] >> 16) == tg &&
                (a0[3] >> 16) == tg && (a1[0] >> 16) == tg && (a1[1] >> 16) == tg &&
                (a1[2] >> 16) == tg && (a1[3] >> 16) == tg;
      if (doH1)
        ok = ok && (b0v[0] >> 16) == tg && (b0v[1] >> 16) == tg && (b0v[2] >> 16) == tg &&
             (b0v[3] >> 16) == tg && (b1v[0] >> 16) == tg && (b1v[1] >> 16) == tg &&
             (b1v[2] >> 16) == tg && (b1v[3] >> 16) == tg;
      if (__all(ok)) break;
    }
    // strip tags -> packed bf16, stage to swizzled LDS
    u32x4 s0, s1;
    s0[0] = (a0[0] & 0xFFFFu) | (a0[1] << 16);
    s0[1] = (a0[2] & 0xFFFFu) | (a0[3] << 16);
    s0[2] = (a1[0] & 0xFFFFu) | (a1[1] << 16);
    s0[3] = (a1[2] & 0xFFFFu) | (a1[3] << 16);
    *(u32x4*)(hlb0 + wsw) = s0;
    if (doH1) {
      s1[0] = (b0v[0] & 0xFFFFu) | (b0v[1] << 16);
      s1[1] = (b0v[2] & 0xFFFFu) | (b0v[3] << 16);
      s1[2] = (b1v[0] & 0xFFFFu) | (b1v[1] << 16);
      s1[3] = (b1v[2] & 0xFFFFu) | (b1v[3] << 16);
      *(u32x4*)(hlb1 + wsw) = s1;
    }
    LGKM0(); SCHEDBAR(); BAR();  // stage ready (+ zpart reuse guard via lgkm)

    // ---- MFMAs
    f32x4 acc0 = {0.f, 0.f, 0.f, 0.f}, acc1 = {0.f, 0.f, 0.f, 0.f};
    if (doL0) {
      #pragma unroll
      for (int kb = 0; kb < 4; kb++)
        acc0 = __builtin_amdgcn_mfma_f32_16x16x32_bf16(
            ea[kb], *(const short8*)(wb0 + (kb << 9)), acc0, 0, 0, 0);
    }
    #pragma unroll
    for (int kb = 0; kb < 4; kb++) {
      short8 h0f = *(const short8*)(hlb0 + ((fb + kb * 64 + q * 16) ^ fx));
      if (doL0)
        acc0 = __builtin_amdgcn_mfma_f32_16x16x32_bf16(
            h0f, *(const short8*)(ub0 + (kb << 9)), acc0, 0, 0, 0);
      acc1 = __builtin_amdgcn_mfma_f32_16x16x32_bf16(
          h0f, *(const short8*)(wb1 + (kb << 9)), acc1, 0, 0, 0);
    }
    if (doH1) {
      #pragma unroll
      for (int kb = 0; kb < 4; kb++) {
        short8 h1f = *(const short8*)(hlb1 + ((fb + kb * 64 + q * 16) ^ fx));
        acc1 = __builtin_amdgcn_mfma_f32_16x16x32_bf16(
            h1f, *(const short8*)(ub1 + (kb << 9)), acc1, 0, 0, 0);
      }
    }

    // ---- z partials
    if (doL0) {
      #pragma unroll
      for (int j = 0; j < 4; j++) zpart[zwr + (((q << 2) + j) << 4)] = acc0[j];
    }
    #pragma unroll
    for (int j = 0; j < 4; j++) zpart[2048 + zwr + (((q << 2) + j) << 4)] = acc1[j];
    LGKM0(); SCHEDBAR(); BAR();

    // ---- combine (L0: threads 0-255 @ step tau; L1: threads 256-511 @ step tau-1)
    if (tlay ? true : doL0) {
      float z[4];
      #pragma unroll
      for (int gg = 0; gg < 4; gg++)
        z[gg] = zpart[(tlay * 8 + gg * 2) * 256 + crow * 16 + cn] +
                zpart[(tlay * 8 + gg * 2 + 1) * 256 + crow * 16 + cn] + bi[gg];
      float cnw = sigm(z[1]) * cst + sigm(z[0]) * tanhp(z[2]);
      float hnw = sigm(z[3]) * tanhp(cnw);
      if (mval) { cst = cnw; hv = hnw; }
      // tagged h store: tag = tau+1, parity = tau&1. Fire-and-forget.
      __hip_atomic_store(hst + (size_t)(tau & 1) * 32768,
                         ((unsigned)(tau + 1) << 16) | (unsigned)f2bf(hv),
                         __ATOMIC_RELAXED, __HIP_MEMORY_SCOPE_AGENT);
      int tout = dir ? TM - 1 - step : step;
      out[(((size_t)((1 + tlay + dir * 3) * BB + brow)) * TM + tout) * NU + ubase + cn] = hv;
    }
  }
}

extern "C" void kernel_launch(void* const* d_in, const int* in_sizes, int n_in,
                              void* d_out, int out_size, void* d_ws, size_t ws_size,
                              hipStream_t stream) {
  const int* seqs = (const int*)d_in[0];
  const float* E = (const float*)d_in[1];
  const float* Wf = (const float*)d_in[2];
  const float* Uf = (const float*)d_in[3];
  const float* bfp = (const float*)d_in[4];
  const float* Wb = (const float*)d_in[5];
  const float* Ub = (const float*)d_in[6];
  const float* bbp = (const float*)d_in[7];
  float* out = (float*)d_out;

  char* ws = (char*)d_ws;
  unsigned int* Hbuf = (unsigned int*)ws;                 // [2 lay][2 par][8 cl][4096] u32 = 512KB
  unsigned short* embb = (unsigned short*)(ws + 1048576); // 8MB bf16 emb

  hipMemsetAsync(Hbuf, 0, 4 * 8 * 4096 * sizeof(unsigned int), stream);

  hipLaunchKernelGGL(embed_kernel, dim3(BB, TT), dim3(256), 0, stream,
                     seqs, E, embb, out);

  int smem = 163840;  // 128K weights + 16K zpart + 2x8K h tiles
  hipFuncSetAttribute(reinterpret_cast<const void*>(lstm_kernel),
                      hipFuncAttributeMaxDynamicSharedMemorySize, smem);
  hipLaunchKernelGGL(lstm_kernel, dim3(128), dim3(512), smem, stream,
                     seqs, Wf, Uf, bfp, Wb, Ub, bbp, embb, Hbuf, out);
}